// Round 6
// baseline (262.079 us; speedup 1.0000x reference)
//
#include <hip/hip_runtime.h>
#include <hip/hip_bf16.h>
#include <cstdint>
#include <cstddef>

#define DIM_ 2048
#define SLEN 2048
#define NQH 32
#define NKVH 8
#define HDIM 64
#define KVDIM 512

typedef __attribute__((ext_vector_type(8))) short short8;
typedef __attribute__((ext_vector_type(4))) float f32x4;
typedef __attribute__((ext_vector_type(16))) float f32x16;
typedef __attribute__((ext_vector_type(4))) unsigned int u32x4;

// 0.125 (1/sqrt(64)) * log2(e): scores land in log2 domain -> exp2 softmax
#define QSCALE 0.1803368801111243f

__device__ __forceinline__ unsigned short f2bf(float f) {
  unsigned u = __builtin_bit_cast(unsigned, f);
  u += 0x7FFFu + ((u >> 16) & 1u);
  return (unsigned short)(u >> 16);
}

__device__ __forceinline__ unsigned cvt_pk_bf16(float lo, float hi) {
  unsigned r;
  asm("v_cvt_pk_bf16_f32 %0, %1, %2" : "=v"(r) : "v"(lo), "v"(hi));
  return r;
}

__device__ __forceinline__ void gload_lds16(const void* g, void* l) {
  __builtin_amdgcn_global_load_lds(
      (const __attribute__((address_space(1))) void*)g,
      (__attribute__((address_space(3))) void*)l, 16, 0, 0);
}

// ---------------- fp32 -> bf16 convert (8 elems/thread, RNE) ----------------
__global__ void cvt_bf16_kernel(const float* __restrict__ in,
                                unsigned short* __restrict__ out, int n) {
  int i = (blockIdx.x * blockDim.x + threadIdx.x) * 8;
  if (i >= n) return;
  float4 a = *(const float4*)(in + i);
  float4 b = *(const float4*)(in + i + 4);
  ushort4 o0, o1;
  o0.x = f2bf(a.x); o0.y = f2bf(a.y); o0.z = f2bf(a.z); o0.w = f2bf(a.w);
  o1.x = f2bf(b.x); o1.y = f2bf(b.y); o1.z = f2bf(b.z); o1.w = f2bf(b.w);
  *(ushort4*)(out + i) = o0;
  *(ushort4*)(out + i + 4) = o1;
}

// ---------------- RoPE tables: cos/sin (SLEN x 32) fp32 ----------------
__global__ void rope_table_kernel(float* __restrict__ cosT, float* __restrict__ sinT) {
  int idx = blockIdx.x * blockDim.x + threadIdx.x;  // SLEN*32
  int s = idx >> 5, i = idx & 31;
  float inv = expf(-(float)i * (9.210340371976184f / 32.0f));
  float fr = (float)s * inv;
  cosT[idx] = cosf(fr);
  sinT[idx] = sinf(fr);
}

// Double-buffered BK=64 staging with T2 st-swizzle: LDS[row][cb] holds
// global[row][cb ^ ((row&7)<<4)] (byte cols). Read applies the same XOR.
#define GSTAGE(buf, kt)                                                        \
  do {                                                                         \
    _Pragma("unroll") for (int r = 0; r < 2; ++r) {                            \
      const int L = r * 512 + tid;                                             \
      const int row = L >> 3;                                                  \
      const int scb = ((L & 7) * 16) ^ ((row & 7) << 4);                       \
      gload_lds16((const char*)A + ((size_t)(row0 + row) * DIM_ + kt) * 2 + scb, \
                  sA[buf] + (size_t)(r * 512 + wv * 64) * 8);                  \
      gload_lds16((const char*)B + ((size_t)(col0 + row) * DIM_ + kt) * 2 + scb, \
                  sB[buf] + (size_t)(r * 512 + wv * 64) * 8);                  \
    }                                                                          \
  } while (0)

#define GCOMPUTE(cur)                                                          \
  do {                                                                         \
    _Pragma("unroll") for (int ks = 0; ks < 2; ++ks) {                         \
      short8 af[2], bfr[4];                                                    \
      _Pragma("unroll") for (int m = 0; m < 2; ++m) {                          \
        const int row = wr + m * 16 + lrow;                                    \
        const int cB = (ks * 64 + lkb) ^ ((row & 7) << 4);                     \
        af[m] = *(const short8*)(sA[cur] + row * 64 + (cB >> 1));              \
      }                                                                        \
      _Pragma("unroll") for (int n = 0; n < 4; ++n) {                          \
        const int row = wc + n * 16 + lrow;                                    \
        const int cB = (ks * 64 + lkb) ^ ((row & 7) << 4);                     \
        bfr[n] = *(const short8*)(sB[cur] + row * 64 + (cB >> 1));             \
      }                                                                        \
      _Pragma("unroll") for (int m = 0; m < 2; ++m)                            \
          _Pragma("unroll") for (int n = 0; n < 4; ++n) acc[m][n] =            \
              __builtin_amdgcn_mfma_f32_16x16x32_bf16(af[m], bfr[n],           \
                                                      acc[m][n], 0, 0, 0);     \
    }                                                                          \
  } while (0)

// ---------------- merged QKV GEMM (8 waves, dbuf BK=64) + RoPE epilogue ----
__global__ __launch_bounds__(512, 2)
void gemm_qkv(const unsigned short* __restrict__ A,
              const unsigned short* __restrict__ B,
              unsigned short* __restrict__ Qr,
              unsigned short* __restrict__ Kr,
              unsigned short* __restrict__ Vtp,
              const float* __restrict__ cosT,
              const float* __restrict__ sinT) {
  __shared__ unsigned short sA[2][128 * 64];
  __shared__ unsigned short sB[2][128 * 64];
  const int tid = threadIdx.x;
  const int wv = tid >> 6, ln = tid & 63;
  const int row0 = blockIdx.x * 128;
  const int col0 = blockIdx.y * 128;
  const int wr = (wv >> 1) * 32, wc = (wv & 1) * 64;
  const int lrow = ln & 15, lkb = (ln >> 4) * 16;  // byte k-offset in 64B half
  f32x4 acc[2][4] = {};

  GSTAGE(0, 0);
  for (int t = 0; t < 32; ++t) {
    __syncthreads();
    if (t + 1 < 32) GSTAGE((t + 1) & 1, (t + 1) * 64);
    GCOMPUTE(t & 1);
  }
  const int orow = (ln >> 4) * 4;
  const int by = blockIdx.y;
  if (by < 16) {  // Q: RoPE + scale
#pragma unroll
    for (int m = 0; m < 2; ++m)
#pragma unroll
      for (int j = 0; j < 4; ++j) {
        const int s = row0 + wr + m * 16 + orow + j;
#pragma unroll
        for (int n = 0; n < 2; ++n) {
          const int d1 = n * 16 + lrow;  // 0..31
          const float cv = cosT[s * 32 + d1], sv = sinT[s * 32 + d1];
          const float x1 = acc[m][n][j], x2 = acc[m][n + 2][j];
          const size_t base = (size_t)s * DIM_ + col0 + wc + d1;
          Qr[base] = f2bf((x1 * cv - x2 * sv) * QSCALE);
          Qr[base + 32] = f2bf((x2 * cv + x1 * sv) * QSCALE);
        }
      }
  } else if (by < 20) {  // K: RoPE
    const int cb = col0 - 2048;
#pragma unroll
    for (int m = 0; m < 2; ++m)
#pragma unroll
      for (int j = 0; j < 4; ++j) {
        const int s = row0 + wr + m * 16 + orow + j;
#pragma unroll
        for (int n = 0; n < 2; ++n) {
          const int d1 = n * 16 + lrow;
          const float cv = cosT[s * 32 + d1], sv = sinT[s * 32 + d1];
          const float x1 = acc[m][n][j], x2 = acc[m][n + 2][j];
          const size_t base = (size_t)s * KVDIM + cb + wc + d1;
          Kr[base] = f2bf(x1 * cv - x2 * sv);
          Kr[base + 32] = f2bf(x2 * cv + x1 * sv);
        }
      }
  } else {  // V transposed
    const int cb = col0 - 2560;
#pragma unroll
    for (int m = 0; m < 2; ++m)
#pragma unroll
      for (int n = 0; n < 4; ++n)
#pragma unroll
        for (int j = 0; j < 4; ++j) {
          const int s = row0 + wr + m * 16 + orow + j;
          const int vc = cb + wc + n * 16 + lrow;
          Vtp[(size_t)vc * SLEN + s] = f2bf(acc[m][n][j]);
        }
  }
}

// ---------------- O-projection GEMM (8 waves, dbuf BK=64, fp32 out) --------
__global__ __launch_bounds__(512, 2)
void gemm_bt_f32(const unsigned short* __restrict__ A,
                 const unsigned short* __restrict__ B, float* __restrict__ C) {
  __shared__ unsigned short sA[2][128 * 64];
  __shared__ unsigned short sB[2][128 * 64];
  const int tid = threadIdx.x;
  const int wv = tid >> 6, ln = tid & 63;
  const int row0 = blockIdx.x * 128;
  const int col0 = blockIdx.y * 128;
  const int wr = (wv >> 1) * 32, wc = (wv & 1) * 64;
  const int lrow = ln & 15, lkb = (ln >> 4) * 16;
  f32x4 acc[2][4] = {};

  GSTAGE(0, 0);
  for (int t = 0; t < 32; ++t) {
    __syncthreads();
    if (t + 1 < 32) GSTAGE((t + 1) & 1, (t + 1) * 64);
    GCOMPUTE(t & 1);
  }
  const int orow = (ln >> 4) * 4;
#pragma unroll
  for (int m = 0; m < 2; ++m)
#pragma unroll
    for (int n = 0; n < 4; ++n)
#pragma unroll
      for (int j = 0; j < 4; ++j)
        C[(size_t)(row0 + wr + m * 16 + orow + j) * DIM_ + col0 + wc + n * 16 + lrow] =
            acc[m][n][j];
}

// ---------------- Flash attention v4: no staging, no barriers --------------
// K/V per kvh = 512 KB -> L2-resident; fragments read direct from global.
// grid 512 1-D: id = chunk_order*32 + hg*8 + kvh  (id%8 = XCD = kvh locality).
// Each block: head h = kvh*4+hg, chunk c = 15 - chunk_order (heavy first),
// 4 independent warps x 32 q-rows. K register-prefetched one tile ahead.
__global__ __launch_bounds__(256, 2)
void attn4_kernel(const unsigned short* __restrict__ Q,
                  const unsigned short* __restrict__ Kc,
                  const unsigned short* __restrict__ Vt,
                  unsigned short* __restrict__ AO) {
  __shared__ __align__(16) char smem[16384];  // epilogue transpose only
  const int id = blockIdx.x;
  const int kvh = id & 7, hg = (id >> 3) & 3;
  const int c = 15 - (id >> 5);
  const int h = kvh * 4 + hg;
  const int tid = threadIdx.x;
  const int w = tid >> 6, l = tid & 63;
  const int l31 = l & 31, hi = l >> 5;
  const int wq0 = c * 128 + w * 32;
  const int qrow = wq0 + l31;
  const int ntw = (wq0 + 95) >> 6;  // tiles visible to this warp

  const unsigned short* Kb = Kc + kvh * HDIM;            // row stride KVDIM
  const unsigned short* Vb = Vt + (size_t)kvh * HDIM * SLEN;  // row stride SLEN

  short8 qf[4];
  {
    const unsigned short* qp = Q + (size_t)qrow * DIM_ + h * HDIM + hi * 8;
#pragma unroll
    for (int d = 0; d < 4; ++d) qf[d] = *(const short8*)(qp + d * 16);
  }
  f32x16 o[2] = {};
  float mrun = -1e30f, lrun = 0.f;

  auto loadK = [&](short8* kf, int t) {
    const unsigned short* kp = Kb + (size_t)(t * 64 + l31) * KVDIM + hi * 8;
#pragma unroll
    for (int d = 0; d < 4; ++d) {
      kf[d] = *(const short8*)(kp + d * 16);
      kf[4 + d] = *(const short8*)(kp + 32 * KVDIM + d * 16);
    }
  };

  auto body = [&](int t, const short8* kf) {
    const int k0 = t * 64;
    // V fragments (consumed after softmax -> latency hidden under it)
    short8 vf0[4], vf1[4];
    {
      const unsigned short* vp = Vb + (size_t)l31 * SLEN + k0 + hi * 8;
#pragma unroll
      for (int d = 0; d < 4; ++d) {
        vf0[d] = *(const short8*)(vp + d * 16);
        vf1[d] = *(const short8*)(vp + (size_t)32 * SLEN + d * 16);
      }
    }
    // S^T = K . Q^T : lane owns q = qrow, k = k0 + (r&3)+8*(r>>2)+4*hi (+32 s1)
    f32x16 s0 = {}, s1 = {};
    __builtin_amdgcn_s_setprio(1);
#pragma unroll
    for (int d = 0; d < 4; ++d) {
      s0 = __builtin_amdgcn_mfma_f32_32x32x16_bf16(kf[d], qf[d], s0, 0, 0, 0);
      s1 = __builtin_amdgcn_mfma_f32_32x32x16_bf16(kf[4 + d], qf[d], s1, 0, 0, 0);
    }
    __builtin_amdgcn_s_setprio(0);

    float p[32];
#pragma unroll
    for (int r = 0; r < 16; ++r) { p[r] = s0[r]; p[16 + r] = s1[r]; }
    if (k0 + 63 > wq0) {  // boundary tile: causal mask
#pragma unroll
      for (int r = 0; r < 16; ++r) {
        const int ka = k0 + (r & 3) + 8 * (r >> 2) + 4 * hi;
        if (ka > qrow) p[r] = -1e30f;
        if (ka + 32 > qrow) p[16 + r] = -1e30f;
      }
    }
    // tree max + cross-half
    float t16[16];
#pragma unroll
    for (int i = 0; i < 16; ++i) t16[i] = fmaxf(p[i], p[i + 16]);
#pragma unroll
    for (int i = 0; i < 8; ++i) t16[i] = fmaxf(t16[i], t16[i + 8]);
#pragma unroll
    for (int i = 0; i < 4; ++i) t16[i] = fmaxf(t16[i], t16[i + 4]);
    float pmax = fmaxf(fmaxf(t16[0], t16[1]), fmaxf(t16[2], t16[3]));
    pmax = fmaxf(pmax, __shfl_xor(pmax, 32));
    if (!__all(pmax - mrun <= 8.0f)) {  // defer-max (T13)
      const float mnew = fmaxf(mrun, pmax);
      const float alpha = exp2f(mrun - mnew);
      mrun = mnew;
      lrun *= alpha;
#pragma unroll
      for (int r = 0; r < 16; ++r) { o[0][r] *= alpha; o[1][r] *= alpha; }
    }
#pragma unroll
    for (int i = 0; i < 32; ++i) p[i] = exp2f(p[i] - mrun);
    float u16[16];
#pragma unroll
    for (int i = 0; i < 16; ++i) u16[i] = p[i] + p[i + 16];
#pragma unroll
    for (int i = 0; i < 8; ++i) u16[i] += u16[i + 8];
#pragma unroll
    for (int i = 0; i < 4; ++i) u16[i] += u16[i + 4];
    float rs = (u16[0] + u16[1]) + (u16[2] + u16[3]);
    rs += __shfl_xor(rs, 32);
    lrun += rs;

    unsigned pa[8], pb[8];
#pragma unroll
    for (int i = 0; i < 8; ++i) {
      pa[i] = cvt_pk_bf16(p[i * 4 + 0], p[i * 4 + 1]);
      pb[i] = cvt_pk_bf16(p[i * 4 + 2], p[i * 4 + 3]);
    }
    // O^T += V^T . P^T ; P fragments via v_permlane32_swap_b32
    __builtin_amdgcn_s_setprio(1);
#pragma unroll
    for (int kb = 0; kb < 4; ++kb) {
      const int i0 = (kb >> 1) * 4 + (kb & 1) * 2;
      const int i1 = i0 + 1;
      unsigned w0 = pa[i0], w2 = pa[i1];
      asm("v_permlane32_swap_b32 %0, %1" : "+v"(w0), "+v"(w2));
      unsigned w1 = pb[i0], w3 = pb[i1];
      asm("v_permlane32_swap_b32 %0, %1" : "+v"(w1), "+v"(w3));
      u32x4 uu = {w0, w1, w2, w3};
      short8 pf = __builtin_bit_cast(short8, uu);
      o[0] = __builtin_amdgcn_mfma_f32_32x32x16_bf16(vf0[kb], pf, o[0], 0, 0, 0);
      o[1] = __builtin_amdgcn_mfma_f32_32x32x16_bf16(vf1[kb], pf, o[1], 0, 0, 0);
    }
    __builtin_amdgcn_s_setprio(0);
  };

  // K double-buffer, statically rotated (rule #20: no runtime-indexed arrays)
  short8 ka[8], kb_[8];
  loadK(ka, 0);
  int t = 0;
  for (;;) {
    if (t + 1 < ntw) loadK(kb_, t + 1);
    body(t, ka);
    if (++t >= ntw) break;
    if (t + 1 < ntw) loadK(ka, t + 1);
    body(t, kb_);
    if (++t >= ntw) break;
  }

  // epilogue: O^T -> LDS (per-warp 4KB, 16B-XOR swizzle) -> coalesced AO rows
  const float inv = 1.0f / lrun;
  char* tw = smem + w * 4096;
#pragma unroll
  for (int db = 0; db < 2; ++db)
#pragma unroll
    for (int g = 0; g < 4; ++g) {
      ushort4 v;
      v.x = f2bf(o[db][g * 4 + 0] * inv);
      v.y = f2bf(o[db][g * 4 + 1] * inv);
      v.z = f2bf(o[db][g * 4 + 2] * inv);
      v.w = f2bf(o[db][g * 4 + 3] * inv);
      const int d0 = db * 32 + g * 8 + hi * 4;
      *(ushort4*)(tw + l31 * 128 + ((d0 * 2) ^ ((l31 & 7) << 4))) = v;
    }
  {
    const int rr = l >> 1, cc = (l & 1) * 32;
    unsigned short* ap = AO + (size_t)(c * 128 + w * 32 + rr) * DIM_ + h * HDIM + cc;
#pragma unroll
    for (int pq = 0; pq < 4; ++pq) {
      const int colb = ((cc + pq * 8) * 2) ^ ((rr & 7) << 4);
      short8 v = *(const short8*)(tw + rr * 128 + colb);
      *(short8*)(ap + pq * 8) = v;
    }
  }
}

extern "C" void kernel_launch(void* const* d_in, const int* in_sizes, int n_in,
                              void* d_out, int out_size, void* d_ws, size_t ws_size,
                              hipStream_t stream) {
  const float* x  = (const float*)d_in[0];
  const float* wq = (const float*)d_in[1];
  const float* wk = (const float*)d_in[2];
  const float* wv = (const float*)d_in[3];
  const float* wo = (const float*)d_in[4];
  float* out = (float*)d_out;
  char* ws = (char*)d_ws;
  const size_t MB = 1u << 20;
  unsigned short* bx   = (unsigned short*)(ws + 0 * MB);    // 8 MB
  unsigned short* bqkv = (unsigned short*)(ws + 8 * MB);    // 12 MB (3072x2048)
  unsigned short* bwo  = (unsigned short*)(ws + 20 * MB);   // 8 MB
  unsigned short* Qr   = (unsigned short*)(ws + 28 * MB);   // 8 MB
  unsigned short* Kr   = (unsigned short*)(ws + 36 * MB);   // 2 MB
  unsigned short* Vt   = (unsigned short*)(ws + 38 * MB);   // 2 MB
  unsigned short* AO   = (unsigned short*)(ws + 40 * MB);   // 8 MB
  float* cosT = (float*)(ws + 48 * MB);                     // 256 KB
  float* sinT = (float*)(ws + 48 * MB + 256 * 1024);        // 256 KB

  rope_table_kernel<<<SLEN * 32 / 256, 256, 0, stream>>>(cosT, sinT);
  cvt_bf16_kernel<<<(2048 * 2048 / 8) / 256, 256, 0, stream>>>(x, bx, 2048 * 2048);
  cvt_bf16_kernel<<<(2048 * 2048 / 8) / 256, 256, 0, stream>>>(wq, bqkv, 2048 * 2048);
  cvt_bf16_kernel<<<(512 * 2048 / 8) / 256, 256, 0, stream>>>(wk, bqkv + 2048 * 2048, 512 * 2048);
  cvt_bf16_kernel<<<(512 * 2048 / 8) / 256, 256, 0, stream>>>(wv, bqkv + 2560 * 2048, 512 * 2048);
  cvt_bf16_kernel<<<(2048 * 2048 / 8) / 256, 256, 0, stream>>>(wo, bwo, 2048 * 2048);

  gemm_qkv<<<dim3(16, 24), 512, 0, stream>>>(bx, bqkv, Qr, Kr, Vt, cosT, sinT);

  attn4_kernel<<<512, 256, 0, stream>>>(Qr, Kr, Vt, AO);

  gemm_bt_f32<<<dim3(16, 16), 512, 0, stream>>>(AO, bwo, out);
}

// Round 7
// 223.196 us; speedup vs baseline: 1.1742x; 1.1742x over previous
//
#include <hip/hip_runtime.h>
#include <hip/hip_bf16.h>
#include <cstdint>
#include <cstddef>

#define DIM_ 2048
#define SLEN 2048
#define NQH 32
#define NKVH 8
#define HDIM 64
#define KVDIM 512

typedef __attribute__((ext_vector_type(8))) short short8;
typedef __attribute__((ext_vector_type(4))) float f32x4;
typedef __attribute__((ext_vector_type(16))) float f32x16;
typedef __attribute__((ext_vector_type(4))) unsigned int u32x4;

// 0.125 (1/sqrt(64)) * log2(e): scores land in log2 domain -> exp2 softmax
#define QSCALE 0.1803368801111243f

__device__ __forceinline__ unsigned short f2bf(float f) {
  unsigned u = __builtin_bit_cast(unsigned, f);
  u += 0x7FFFu + ((u >> 16) & 1u);
  return (unsigned short)(u >> 16);
}

__device__ __forceinline__ unsigned cvt_pk_bf16(float lo, float hi) {
  unsigned r;
  asm("v_cvt_pk_bf16_f32 %0, %1, %2" : "=v"(r) : "v"(lo), "v"(hi));
  return r;
}

__device__ __forceinline__ void gload_lds16(const void* g, void* l) {
  __builtin_amdgcn_global_load_lds(
      (const __attribute__((address_space(1))) void*)g,
      (__attribute__((address_space(3))) void*)l, 16, 0, 0);
}

// ---------------- fp32 -> bf16 convert (8 elems/thread, RNE) ----------------
__global__ void cvt_bf16_kernel(const float* __restrict__ in,
                                unsigned short* __restrict__ out, int n) {
  int i = (blockIdx.x * blockDim.x + threadIdx.x) * 8;
  if (i >= n) return;
  float4 a = *(const float4*)(in + i);
  float4 b = *(const float4*)(in + i + 4);
  ushort4 o0, o1;
  o0.x = f2bf(a.x); o0.y = f2bf(a.y); o0.z = f2bf(a.z); o0.w = f2bf(a.w);
  o1.x = f2bf(b.x); o1.y = f2bf(b.y); o1.z = f2bf(b.z); o1.w = f2bf(b.w);
  *(ushort4*)(out + i) = o0;
  *(ushort4*)(out + i + 4) = o1;
}

// ---------------- RoPE tables: cos/sin (SLEN x 32) fp32 ----------------
__global__ void rope_table_kernel(float* __restrict__ cosT, float* __restrict__ sinT) {
  int idx = blockIdx.x * blockDim.x + threadIdx.x;  // SLEN*32
  int s = idx >> 5, i = idx & 31;
  float inv = expf(-(float)i * (9.210340371976184f / 32.0f));
  float fr = (float)s * inv;
  cosT[idx] = cosf(fr);
  sinT[idx] = sinf(fr);
}

// Double-buffered BK=64 staging with T2 st-swizzle: LDS[row][cb] holds
// global[row][cb ^ ((row&7)<<4)] (byte cols). Read applies the same XOR.
#define GSTAGE(buf, kt)                                                        \
  do {                                                                         \
    _Pragma("unroll") for (int r = 0; r < 2; ++r) {                            \
      const int L = r * 512 + tid;                                             \
      const int row = L >> 3;                                                  \
      const int scb = ((L & 7) * 16) ^ ((row & 7) << 4);                       \
      gload_lds16((const char*)A + ((size_t)(row0 + row) * DIM_ + kt) * 2 + scb, \
                  sA[buf] + (size_t)(r * 512 + wv * 64) * 8);                  \
      gload_lds16((const char*)B + ((size_t)(col0 + row) * DIM_ + kt) * 2 + scb, \
                  sB[buf] + (size_t)(r * 512 + wv * 64) * 8);                  \
    }                                                                          \
  } while (0)

#define GCOMPUTE(cur)                                                          \
  do {                                                                         \
    _Pragma("unroll") for (int ks = 0; ks < 2; ++ks) {                         \
      short8 af[2], bfr[4];                                                    \
      _Pragma("unroll") for (int m = 0; m < 2; ++m) {                          \
        const int row = wr + m * 16 + lrow;                                    \
        const int cB = (ks * 64 + lkb) ^ ((row & 7) << 4);                     \
        af[m] = *(const short8*)(sA[cur] + row * 64 + (cB >> 1));              \
      }                                                                        \
      _Pragma("unroll") for (int n = 0; n < 4; ++n) {                          \
        const int row = wc + n * 16 + lrow;                                    \
        const int cB = (ks * 64 + lkb) ^ ((row & 7) << 4);                     \
        bfr[n] = *(const short8*)(sB[cur] + row * 64 + (cB >> 1));             \
      }                                                                        \
      _Pragma("unroll") for (int m = 0; m < 2; ++m)                            \
          _Pragma("unroll") for (int n = 0; n < 4; ++n) acc[m][n] =            \
              __builtin_amdgcn_mfma_f32_16x16x32_bf16(af[m], bfr[n],           \
                                                      acc[m][n], 0, 0, 0);     \
    }                                                                          \
  } while (0)

// ---------------- merged QKV GEMM (8 waves, dbuf BK=64) + RoPE epilogue ----
__global__ __launch_bounds__(512, 2)
void gemm_qkv(const unsigned short* __restrict__ A,
              const unsigned short* __restrict__ B,
              unsigned short* __restrict__ Qr,
              unsigned short* __restrict__ Kr,
              unsigned short* __restrict__ Vtp,
              const float* __restrict__ cosT,
              const float* __restrict__ sinT) {
  __shared__ unsigned short sA[2][128 * 64];
  __shared__ unsigned short sB[2][128 * 64];
  const int tid = threadIdx.x;
  const int wv = tid >> 6, ln = tid & 63;
  const int row0 = blockIdx.x * 128;
  const int col0 = blockIdx.y * 128;
  const int wr = (wv >> 1) * 32, wc = (wv & 1) * 64;
  const int lrow = ln & 15, lkb = (ln >> 4) * 16;  // byte k-offset in 64B half
  f32x4 acc[2][4] = {};

  GSTAGE(0, 0);
  for (int t = 0; t < 32; ++t) {
    __syncthreads();
    if (t + 1 < 32) GSTAGE((t + 1) & 1, (t + 1) * 64);
    GCOMPUTE(t & 1);
  }
  const int orow = (ln >> 4) * 4;
  const int by = blockIdx.y;
  if (by < 16) {  // Q: RoPE + scale
#pragma unroll
    for (int m = 0; m < 2; ++m)
#pragma unroll
      for (int j = 0; j < 4; ++j) {
        const int s = row0 + wr + m * 16 + orow + j;
#pragma unroll
        for (int n = 0; n < 2; ++n) {
          const int d1 = n * 16 + lrow;  // 0..31
          const float cv = cosT[s * 32 + d1], sv = sinT[s * 32 + d1];
          const float x1 = acc[m][n][j], x2 = acc[m][n + 2][j];
          const size_t base = (size_t)s * DIM_ + col0 + wc + d1;
          Qr[base] = f2bf((x1 * cv - x2 * sv) * QSCALE);
          Qr[base + 32] = f2bf((x2 * cv + x1 * sv) * QSCALE);
        }
      }
  } else if (by < 20) {  // K: RoPE
    const int cb = col0 - 2048;
#pragma unroll
    for (int m = 0; m < 2; ++m)
#pragma unroll
      for (int j = 0; j < 4; ++j) {
        const int s = row0 + wr + m * 16 + orow + j;
#pragma unroll
        for (int n = 0; n < 2; ++n) {
          const int d1 = n * 16 + lrow;
          const float cv = cosT[s * 32 + d1], sv = sinT[s * 32 + d1];
          const float x1 = acc[m][n][j], x2 = acc[m][n + 2][j];
          const size_t base = (size_t)s * KVDIM + cb + wc + d1;
          Kr[base] = f2bf(x1 * cv - x2 * sv);
          Kr[base + 32] = f2bf(x2 * cv + x1 * sv);
        }
      }
  } else {  // V transposed
    const int cb = col0 - 2560;
#pragma unroll
    for (int m = 0; m < 2; ++m)
#pragma unroll
      for (int n = 0; n < 4; ++n)
#pragma unroll
        for (int j = 0; j < 4; ++j) {
          const int s = row0 + wr + m * 16 + orow + j;
          const int vc = cb + wc + n * 16 + lrow;
          Vtp[(size_t)vc * SLEN + s] = f2bf(acc[m][n][j]);
        }
  }
}

// ---------------- O-projection GEMM (8 waves, dbuf BK=64, fp32 out) --------
__global__ __launch_bounds__(512, 2)
void gemm_bt_f32(const unsigned short* __restrict__ A,
                 const unsigned short* __restrict__ B, float* __restrict__ C) {
  __shared__ unsigned short sA[2][128 * 64];
  __shared__ unsigned short sB[2][128 * 64];
  const int tid = threadIdx.x;
  const int wv = tid >> 6, ln = tid & 63;
  const int row0 = blockIdx.x * 128;
  const int col0 = blockIdx.y * 128;
  const int wr = (wv >> 1) * 32, wc = (wv & 1) * 64;
  const int lrow = ln & 15, lkb = (ln >> 4) * 16;
  f32x4 acc[2][4] = {};

  GSTAGE(0, 0);
  for (int t = 0; t < 32; ++t) {
    __syncthreads();
    if (t + 1 < 32) GSTAGE((t + 1) & 1, (t + 1) * 64);
    GCOMPUTE(t & 1);
  }
  const int orow = (ln >> 4) * 4;
#pragma unroll
  for (int m = 0; m < 2; ++m)
#pragma unroll
    for (int n = 0; n < 4; ++n)
#pragma unroll
      for (int j = 0; j < 4; ++j)
        C[(size_t)(row0 + wr + m * 16 + orow + j) * DIM_ + col0 + wc + n * 16 + lrow] =
            acc[m][n][j];
}

#define WAITV8() asm volatile("s_waitcnt vmcnt(8)" ::: "memory")
#define WAITV0() asm volatile("s_waitcnt vmcnt(0)" ::: "memory")
#define WAITL0() asm volatile("s_waitcnt lgkmcnt(0)" ::: "memory")

// ---------------- Flash attention v5: 1-wave blocks, zero barriers ---------
// Per block: one 32-row q-chunk of one head. K/V tiles (64 kv x 64 d) staged
// to LDS via global_load_lds (coalesced, pre-swizzled source), SINGLE buffer:
// ds_read frags -> lgkmcnt(0) -> issue next tile's loads. Counted vmcnt(8)
// waits (T4); no __syncthreads anywhere. Grid 2048, heavy chunks first.
__global__ __launch_bounds__(64, 2)
void attn5_kernel(const unsigned short* __restrict__ Q,
                  const unsigned short* __restrict__ Kc,
                  const unsigned short* __restrict__ Vt,
                  unsigned short* __restrict__ AO) {
  __shared__ __align__(16) char smem[16384];  // [K 8K][V 8K]
  const int id = blockIdx.x;
  const int h = id & 31;
  const int c = 63 - (id >> 5);       // 32-row chunk, heavy first
  const int kvh = h >> 2;
  const int l = threadIdx.x;
  const int l31 = l & 31, hi = l >> 5;
  const int wq0 = c * 32;
  const int qrow = wq0 + l31;
  const int nt = (c + 2) >> 1;        // 64-wide kv tiles this chunk needs

  const char* Kb = (const char*)(Kc + kvh * HDIM);              // row str 1024B
  const char* Vb = (const char*)(Vt + (size_t)kvh * HDIM * SLEN);  // row str 4096B

  // staging source pre-swizzle: LDS[row][cb] = global[row][cb ^ ((row&7)<<4)]
  const int lrow8 = l >> 3;                       // 0..7 (row within 8-group)
  const int scb = ((l & 7) * 16) ^ (lrow8 << 4);  // swizzled source col-byte

  auto stageK = [&](int t) {
#pragma unroll
    for (int i = 0; i < 8; ++i)
      gload_lds16(Kb + (size_t)(t * 64 + i * 8 + lrow8) * (KVDIM * 2) + scb,
                  smem + i * 1024);
  };
  auto stageV = [&](int t) {
#pragma unroll
    for (int i = 0; i < 8; ++i)
      gload_lds16(Vb + (size_t)(i * 8 + lrow8) * (SLEN * 2) + t * 128 + scb,
                  smem + 8192 + i * 1024);
  };

  short8 qf[4];
  {
    const unsigned short* qp = Q + (size_t)qrow * DIM_ + h * HDIM + hi * 8;
#pragma unroll
    for (int d = 0; d < 4; ++d) qf[d] = *(const short8*)(qp + d * 16);
  }
  f32x16 o[2] = {};
  float mrun = -1e30f, lrun = 0.f;

  stageK(0);
  stageV(0);

  for (int t = 0; t < nt; ++t) {
    const int k0 = t * 64;
    const bool last = (t + 1 >= nt);
    const bool skipHi = (k0 >= wq0);  // upper 32 kv rows fully masked (even c)

    WAITV8();  // K(t) landed (V(t) may still be in flight)
    short8 kfr[8];
#pragma unroll
    for (int d = 0; d < 4; ++d) {
      const int colb = (d * 32 + hi * 16) ^ ((l31 & 7) << 4);
      kfr[d] = *(const short8*)(smem + l31 * 128 + colb);
      kfr[4 + d] = *(const short8*)(smem + (32 + l31) * 128 + colb);
    }
    WAITL0();  // frags in VGPRs before overwriting buffer
    __builtin_amdgcn_sched_barrier(0);
    if (!last) stageK(t + 1);

    // S^T = K . Q^T : lane owns q = qrow, k = k0 + (r&3)+8*(r>>2)+4*hi (+32 s1)
    f32x16 s0 = {}, s1 = {};
    __builtin_amdgcn_s_setprio(1);
#pragma unroll
    for (int d = 0; d < 4; ++d)
      s0 = __builtin_amdgcn_mfma_f32_32x32x16_bf16(kfr[d], qf[d], s0, 0, 0, 0);
    if (!skipHi) {
#pragma unroll
      for (int d = 0; d < 4; ++d)
        s1 = __builtin_amdgcn_mfma_f32_32x32x16_bf16(kfr[4 + d], qf[d], s1, 0, 0, 0);
    }
    __builtin_amdgcn_s_setprio(0);

    float p[32];
#pragma unroll
    for (int r = 0; r < 16; ++r) { p[r] = s0[r]; p[16 + r] = s1[r]; }
    if (k0 + 63 > wq0) {  // boundary: causal mask
#pragma unroll
      for (int r = 0; r < 16; ++r) {
        const int ka = k0 + (r & 3) + 8 * (r >> 2) + 4 * hi;
        if (ka > qrow) p[r] = -1e30f;
        if (skipHi || ka + 32 > qrow) p[16 + r] = -1e30f;
      }
    }
    // tree max + cross-half
    float t16[16];
#pragma unroll
    for (int i = 0; i < 16; ++i) t16[i] = fmaxf(p[i], p[i + 16]);
#pragma unroll
    for (int i = 0; i < 8; ++i) t16[i] = fmaxf(t16[i], t16[i + 8]);
#pragma unroll
    for (int i = 0; i < 4; ++i) t16[i] = fmaxf(t16[i], t16[i + 4]);
    float pmax = fmaxf(fmaxf(t16[0], t16[1]), fmaxf(t16[2], t16[3]));
    pmax = fmaxf(pmax, __shfl_xor(pmax, 32));
    if (!__all(pmax - mrun <= 8.0f)) {  // defer-max (T13)
      const float mnew = fmaxf(mrun, pmax);
      const float alpha = exp2f(mrun - mnew);
      mrun = mnew;
      lrun *= alpha;
#pragma unroll
      for (int r = 0; r < 16; ++r) { o[0][r] *= alpha; o[1][r] *= alpha; }
    }
#pragma unroll
    for (int i = 0; i < 32; ++i) p[i] = exp2f(p[i] - mrun);
    float u16[16];
#pragma unroll
    for (int i = 0; i < 16; ++i) u16[i] = p[i] + p[i + 16];
#pragma unroll
    for (int i = 0; i < 8; ++i) u16[i] += u16[i + 8];
#pragma unroll
    for (int i = 0; i < 4; ++i) u16[i] += u16[i + 4];
    float rs = (u16[0] + u16[1]) + (u16[2] + u16[3]);
    rs += __shfl_xor(rs, 32);
    lrun += rs;

    unsigned pa[8], pb[8];
#pragma unroll
    for (int i = 0; i < 8; ++i) {
      pa[i] = cvt_pk_bf16(p[i * 4 + 0], p[i * 4 + 1]);
      pb[i] = cvt_pk_bf16(p[i * 4 + 2], p[i * 4 + 3]);
    }

    if (!last) { WAITV8(); } else { WAITV0(); }  // V(t) landed
    short8 vfr[8];
#pragma unroll
    for (int kb = 0; kb < 4; ++kb) {
      const int colb = (kb * 32 + hi * 16) ^ ((l31 & 7) << 4);
      vfr[kb] = *(const short8*)(smem + 8192 + l31 * 128 + colb);
      vfr[4 + kb] = *(const short8*)(smem + 8192 + (32 + l31) * 128 + colb);
    }
    WAITL0();
    __builtin_amdgcn_sched_barrier(0);
    if (!last) stageV(t + 1);

    // O^T += V^T . P^T ; P fragments via v_permlane32_swap_b32
    __builtin_amdgcn_s_setprio(1);
#pragma unroll
    for (int kb = 0; kb < 4; ++kb) {
      if (skipHi && kb >= 2) break;  // p[16..31]=0 -> zero contribution
      const int i0 = (kb >> 1) * 4 + (kb & 1) * 2;
      const int i1 = i0 + 1;
      unsigned w0 = pa[i0], w2 = pa[i1];
      asm("v_permlane32_swap_b32 %0, %1" : "+v"(w0), "+v"(w2));
      unsigned w1 = pb[i0], w3 = pb[i1];
      asm("v_permlane32_swap_b32 %0, %1" : "+v"(w1), "+v"(w3));
      u32x4 uu = {w0, w1, w2, w3};
      short8 pf = __builtin_bit_cast(short8, uu);
      o[0] = __builtin_amdgcn_mfma_f32_32x32x16_bf16(vfr[kb], pf, o[0], 0, 0, 0);
      o[1] = __builtin_amdgcn_mfma_f32_32x32x16_bf16(vfr[4 + kb], pf, o[1], 0, 0, 0);
    }
    __builtin_amdgcn_s_setprio(0);
  }

  // epilogue: O^T -> LDS (4KB, 16B-XOR swizzle) -> coalesced AO rows
  const float inv = 1.0f / lrun;
#pragma unroll
  for (int db = 0; db < 2; ++db)
#pragma unroll
    for (int g = 0; g < 4; ++g) {
      ushort4 v;
      v.x = f2bf(o[db][g * 4 + 0] * inv);
      v.y = f2bf(o[db][g * 4 + 1] * inv);
      v.z = f2bf(o[db][g * 4 + 2] * inv);
      v.w = f2bf(o[db][g * 4 + 3] * inv);
      const int d0 = db * 32 + g * 8 + hi * 4;
      *(ushort4*)(smem + l31 * 128 + ((d0 * 2) ^ ((l31 & 7) << 4))) = v;
    }
  {
    const int rr = l >> 1, cc2 = (l & 1) * 32;
    unsigned short* ap = AO + (size_t)(wq0 + rr) * DIM_ + h * HDIM + cc2;
#pragma unroll
    for (int pq = 0; pq < 4; ++pq) {
      const int colb = ((cc2 + pq * 8) * 2) ^ ((rr & 7) << 4);
      short8 v = *(const short8*)(smem + rr * 128 + colb);
      *(short8*)(ap + pq * 8) = v;
    }
  }
}

extern "C" void kernel_launch(void* const* d_in, const int* in_sizes, int n_in,
                              void* d_out, int out_size, void* d_ws, size_t ws_size,
                              hipStream_t stream) {
  const float* x  = (const float*)d_in[0];
  const float* wq = (const float*)d_in[1];
  const float* wk = (const float*)d_in[2];
  const float* wv = (const float*)d_in[3];
  const float* wo = (const float*)d_in[4];
  float* out = (float*)d_out;
  char* ws = (char*)d_ws;
  const size_t MB = 1u << 20;
  unsigned short* bx   = (unsigned short*)(ws + 0 * MB);    // 8 MB
  unsigned short* bqkv = (unsigned short*)(ws + 8 * MB);    // 12 MB (3072x2048)
  unsigned short* bwo  = (unsigned short*)(ws + 20 * MB);   // 8 MB
  unsigned short* Qr   = (unsigned short*)(ws + 28 * MB);   // 8 MB
  unsigned short* Kr   = (unsigned short*)(ws + 36 * MB);   // 2 MB
  unsigned short* Vt   = (unsigned short*)(ws + 38 * MB);   // 2 MB
  unsigned short* AO   = (unsigned short*)(ws + 40 * MB);   // 8 MB
  float* cosT = (float*)(ws + 48 * MB);                     // 256 KB
  float* sinT = (float*)(ws + 48 * MB + 256 * 1024);        // 256 KB

  rope_table_kernel<<<SLEN * 32 / 256, 256, 0, stream>>>(cosT, sinT);
  cvt_bf16_kernel<<<(2048 * 2048 / 8) / 256, 256, 0, stream>>>(x, bx, 2048 * 2048);
  cvt_bf16_kernel<<<(2048 * 2048 / 8) / 256, 256, 0, stream>>>(wq, bqkv, 2048 * 2048);
  cvt_bf16_kernel<<<(512 * 2048 / 8) / 256, 256, 0, stream>>>(wk, bqkv + 2048 * 2048, 512 * 2048);
  cvt_bf16_kernel<<<(512 * 2048 / 8) / 256, 256, 0, stream>>>(wv, bqkv + 2560 * 2048, 512 * 2048);
  cvt_bf16_kernel<<<(2048 * 2048 / 8) / 256, 256, 0, stream>>>(wo, bwo, 2048 * 2048);

  gemm_qkv<<<dim3(16, 24), 512, 0, stream>>>(bx, bqkv, Qr, Kr, Vt, cosT, sinT);

  attn5_kernel<<<2048, 64, 0, stream>>>(Qr, Kr, Vt, AO);

  gemm_bt_f32<<<dim3(16, 16), 512, 0, stream>>>(AO, bwo, out);
}